// Round 9
// baseline (5175.932 us; speedup 1.0000x reference)
//
#include <hip/hip_runtime.h>
#include <hip/hip_bf16.h>

// Bidirectional LSTM, B=32 T=512 D=H=512. f32 I/O, bf16 MFMA internally.
//
// R15 = R9 protocol VERBATIM (best measured: 2110us), decomposition
//       32wg/dir x 16cols -> 16wg/dir x 32cols at UNCHANGED 256t/4 waves.
//  - R13 tried participant-halving via 512t/8 waves and died on the
//    128-VGPR allocator cap (spills, 5670us). Here: 4 waves, 1 wave/SIMD,
//    512-VGPR budget; weights 2x (wih[2][16], whh[2][16] = 256 VGPR),
//    4 independent acc chains, ~440 VGPR peak (m24: safe through 450).
//  - Poll/exchange verbatim R9: coalesced lane+64j dense sweep (512B
//    contiguous per load instr), late poll position, tagged 8B payloads
//    (tag=step+1 | 2 bf16 cols), scattered-dword hA staging, 2 lgkm-only
//    barriers/step. R12/R14 proved scatter layout (+200us) and early
//    sweep (+300us) both lose.
//  - Mechanism under test: poll burst 4->2 MB/step agent-scope LLC reads;
//    producer convoy max-of-16 instead of max-of-32 per dir.

typedef __bf16 bf16;
typedef __attribute__((ext_vector_type(8))) __bf16 bf16x8;
typedef __attribute__((ext_vector_type(4))) float f32x4;
typedef unsigned long long u64;

__device__ __forceinline__ float sigmoidf_(float x) {
  return 1.f / (1.f + __expf(-x));
}
__device__ __forceinline__ float tanhf_(float x) {
  float e = __expf(-2.f * fabsf(x));
  return copysignf((1.f - e) / (1.f + e), x);
}
__device__ __forceinline__ u64 ald64(const u64* p) {
  return __hip_atomic_load(p, __ATOMIC_RELAXED, __HIP_MEMORY_SCOPE_AGENT);
}
__device__ __forceinline__ void ast64(u64* p, u64 v) {
  __hip_atomic_store(p, v, __ATOMIC_RELAXED, __HIP_MEMORY_SCOPE_AGENT);
}
__device__ __forceinline__ bf16x8 cvt8v(float4 a, float4 b) {
  bf16x8 v;
  v[0] = (bf16)a.x; v[1] = (bf16)a.y; v[2] = (bf16)a.z; v[3] = (bf16)a.w;
  v[4] = (bf16)b.x; v[5] = (bf16)b.y; v[6] = (bf16)b.z; v[7] = (bf16)b.w;
  return v;
}
// Barrier with LDS-visibility only: does NOT drain vmcnt.
__device__ __forceinline__ void bar_lgkm() {
  asm volatile("s_waitcnt lgkmcnt(0)\n\ts_barrier" ::: "memory");
}

// ---------------- lengths ----------------
__global__ void lengths_kernel(const int* __restrict__ mask, int* __restrict__ lengths) {
  __shared__ int part[32][8];
  int t = threadIdx.x;
  int b = t >> 3, sub = t & 7;
  int s = 0;
#pragma unroll 8
  for (int k = 0; k < 64; ++k) s += mask[b * 512 + sub + 8 * k];
  part[b][sub] = s;
  __syncthreads();
  if (sub == 0) {
    int tot = 0;
#pragma unroll
    for (int k = 0; k < 8; ++k) tot += part[b][k];
    lengths[b] = tot;
  }
}

// ---------------- fused persistent LSTM ----------------
__global__ __launch_bounds__(256, 1) void lstm_fused(
    const float* __restrict__ x,                                  // [32][512][512] f32
    const float* __restrict__ Wih_f, const float* __restrict__ bih_f,
    const float* __restrict__ Whh_f,
    const float* __restrict__ Wih_b, const float* __restrict__ bih_b,
    const float* __restrict__ Whh_b,
    const int* __restrict__ lengths,
    u64* __restrict__ hbuf,             // [2 dir][2 par][32 batch][256] u64 entries
    float* __restrict__ out) {          // [32][512][1024] f32
  const int s = blockIdx.x;             // h-col slice: cols [32s, 32s+32)
  const int dir = blockIdx.y;
  const float* Wih = dir ? Wih_b : Wih_f;
  const float* Whh = dir ? Whh_b : Whh_f;
  const float* bih = dir ? bih_b : bih_f;

  const int tid = threadIdx.x;
  const int lane = tid & 63, wave = tid >> 6;
  const int l15 = lane & 15, quad = lane >> 4;

  __shared__ __align__(16) bf16 xA[2][32 * 512];  // 2x32 KB x double buffer
  __shared__ __align__(16) bf16 hA[32 * 512];     // 32 KB h (single)
  __shared__ float vbuf[4][32][33];               // [gate][batch][col 0..31]
  __shared__ int lenL[32];

  // Weight slices f32 -> bf16 registers (wave = gate; two 16-col tiles).
  bf16x8 wih[2][16], whh[2][16];
#pragma unroll
  for (int nt = 0; nt < 2; ++nt) {
    int grow = wave * 512 + s * 32 + nt * 16 + l15;
#pragma unroll
    for (int k = 0; k < 16; ++k) {
      const float* pw = Wih + (size_t)grow * 512 + k * 32 + quad * 8;
      const float* ph = Whh + (size_t)grow * 512 + k * 32 + quad * 8;
      wih[nt][k] = cvt8v(*(const float4*)pw, *(const float4*)(pw + 4));
      whh[nt][k] = cvt8v(*(const float4*)ph, *(const float4*)(ph + 4));
    }
  }
  const float bv0 = bih[wave * 512 + s * 32 + l15];
  const float bv1 = bih[wave * 512 + s * 32 + 16 + l15];
  if (tid < 32) lenL[tid] = lengths[tid];
  __syncthreads();

  const int cb = tid >> 3, cj = (tid & 7) * 2;    // batch, col-pair base
  int lenR[8];
#pragma unroll
  for (int i = 0; i < 8; ++i) lenR[i] = lenL[(i * 256 + tid) >> 6];
  const int lenO = lenL[cb];

  float creg0 = 0.f, creg1 = 0.f, creg2 = 0.f, creg3 = 0.f;
  u64* hb = hbuf + (size_t)dir * (2 * 32 * 256);

  // Prologue: load x(0), stage xA[0], then issue prefetch of x(1).
  float4 xp[8][2];
#pragma unroll
  for (int i = 0; i < 8; ++i) {
    int c = i * 256 + tid;
    int m = c >> 6, kbp = c & 63;
    int kb = kbp ^ (m & 7);
    int tr = (dir == 0) ? 0 : ((511 + lenR[i]) & 511);
    const float4* p = (const float4*)(x + ((size_t)m * 512 + tr) * 512 + kb * 8);
    xp[i][0] = p[0]; xp[i][1] = p[1];
  }
#pragma unroll
  for (int i = 0; i < 8; ++i) {
    int c = i * 256 + tid;
    *(bf16x8*)(xA[0] + c * 8) = cvt8v(xp[i][0], xp[i][1]);
  }
#pragma unroll
  for (int i = 0; i < 8; ++i) {
    int c = i * 256 + tid;
    int m = c >> 6, kbp = c & 63;
    int kb = kbp ^ (m & 7);
    int tr = (dir == 0) ? 1 : ((510 + lenR[i]) & 511);
    const float4* p = (const float4*)(x + ((size_t)m * 512 + tr) * 512 + kb * 8);
    xp[i][0] = p[0]; xp[i][1] = p[1];
  }
  bar_lgkm();  // xA[0] staged

  for (int step = 0; step < 512; ++step) {
    const int par = step & 1;
    const u64* hprev = hb + (size_t)par * (32 * 256);
    u64* hnext = hb + (size_t)(par ^ 1) * (32 * 256);
    const bf16* xcur = xA[par];
    bf16* xnxt = xA[par ^ 1];

    // ---- (1) stage xA(t+1) from regs ----
    if (step < 511) {
#pragma unroll
      for (int i = 0; i < 8; ++i) {
        int c = i * 256 + tid;
        *(bf16x8*)(xnxt + c * 8) = cvt8v(xp[i][0], xp[i][1]);
      }
    }
    // ---- (2) x(t+2) prefetch issue (R9 position) ----
    if (step < 510) {
#pragma unroll
      for (int i = 0; i < 8; ++i) {
        int c = i * 256 + tid;
        int m = c >> 6, kbp = c & 63;
        int kb = kbp ^ (m & 7);
        int tr = (dir == 0) ? (step + 2) : ((509 - step + lenR[i]) & 511);
        const float4* p = (const float4*)(x + ((size_t)m * 512 + tr) * 512 + kb * 8);
        xp[i][0] = p[0]; xp[i][1] = p[1];
      }
    }

    // ---- (3) x-part MFMAs: v = x@Wih^T + bias (2 col-tiles) ----
    f32x4 acc00 = {bv0, bv0, bv0, bv0};  // tile0, batches 0-15
    f32x4 acc01 = {bv0, bv0, bv0, bv0};  // tile0, batches 16-31
    f32x4 acc10 = {bv1, bv1, bv1, bv1};  // tile1, batches 0-15
    f32x4 acc11 = {bv1, bv1, bv1, bv1};  // tile1, batches 16-31
#pragma unroll
    for (int k = 0; k < 16; ++k) {
      int kb = k * 4 + quad;
      int sw = (kb ^ (l15 & 7)) * 8;
      bf16x8 ax0 = *(const bf16x8*)(xcur + l15 * 512 + sw);
      bf16x8 ax1 = *(const bf16x8*)(xcur + (16 + l15) * 512 + sw);
      acc00 = __builtin_amdgcn_mfma_f32_16x16x32_bf16(ax0, wih[0][k], acc00, 0, 0, 0);
      acc01 = __builtin_amdgcn_mfma_f32_16x16x32_bf16(ax1, wih[0][k], acc01, 0, 0, 0);
      acc10 = __builtin_amdgcn_mfma_f32_16x16x32_bf16(ax0, wih[1][k], acc10, 0, 0, 0);
      acc11 = __builtin_amdgcn_mfma_f32_16x16x32_bf16(ax1, wih[1][k], acc11, 0, 0, 0);
    }
    __builtin_amdgcn_sched_barrier(0);

    // ---- (4) poll (R9 verbatim): coalesced dense batched re-sweep ----
    // wave w covers batches [8w,8w+8); entry e of batch m = cols (2e,2e+1);
    // lane reads entries lane+64j (512B contiguous per load instruction).
    u64 hv[8][4];
    {
      const unsigned target = (unsigned)step;
      while (true) {
#pragma unroll
        for (int b = 0; b < 8; ++b) {
          const u64* rp = hprev + (wave * 8 + b) * 256 + lane;
#pragma unroll
          for (int j = 0; j < 4; ++j) hv[b][j] = ald64(rp + 64 * j);
        }
        int ok = 1;
#pragma unroll
        for (int b = 0; b < 8; ++b)
#pragma unroll
          for (int j = 0; j < 4; ++j)
            ok &= (int)((unsigned)(hv[b][j] >> 32) >= target);
        if (__all(ok)) break;
        __builtin_amdgcn_s_sleep(1);
      }
    }

    // ---- (5) stage payloads -> swizzled hA (R9 verbatim) ----
#pragma unroll
    for (int b = 0; b < 8; ++b) {
      int m = wave * 8 + b;
#pragma unroll
      for (int j = 0; j < 4; ++j) {
        int b8 = (lane >> 2) + 16 * j;          // 8-col block of col 2*(lane+64j)
        int b8s = b8 ^ (m & 7);                 // same XOR swizzle as MFMA reads
        *(unsigned*)(hA + m * 512 + b8s * 8 + 2 * (lane & 3)) = (unsigned)hv[b][j];
      }
    }
    bar_lgkm();  // C: hA + xnxt visible (x prefetch rides through)

    // ---- (6) h-part MFMAs: v += h@Whh^T (2 col-tiles) ----
#pragma unroll
    for (int k = 0; k < 16; ++k) {
      int kb = k * 4 + quad;
      int sw = (kb ^ (l15 & 7)) * 8;
      bf16x8 ah0 = *(const bf16x8*)(hA + l15 * 512 + sw);
      bf16x8 ah1 = *(const bf16x8*)(hA + (16 + l15) * 512 + sw);
      acc00 = __builtin_amdgcn_mfma_f32_16x16x32_bf16(ah0, whh[0][k], acc00, 0, 0, 0);
      acc01 = __builtin_amdgcn_mfma_f32_16x16x32_bf16(ah1, whh[0][k], acc01, 0, 0, 0);
      acc10 = __builtin_amdgcn_mfma_f32_16x16x32_bf16(ah0, whh[1][k], acc10, 0, 0, 0);
      acc11 = __builtin_amdgcn_mfma_f32_16x16x32_bf16(ah1, whh[1][k], acc11, 0, 0, 0);
    }
#pragma unroll
    for (int r = 0; r < 4; ++r) {
      vbuf[wave][quad * 4 + r][l15] = acc00[r];
      vbuf[wave][16 + quad * 4 + r][l15] = acc01[r];
      vbuf[wave][quad * 4 + r][16 + l15] = acc10[r];
      vbuf[wave][16 + quad * 4 + r][16 + l15] = acc11[r];
    }
    bar_lgkm();  // D: vbuf ready

    // ---- (7) cell update: 2 col-pairs per thread (cj and cj+16) ----
    float i0 = vbuf[0][cb][cj],      f0 = vbuf[1][cb][cj];
    float g0 = vbuf[2][cb][cj],      o0 = vbuf[3][cb][cj];
    float i1 = vbuf[0][cb][cj + 1],  f1 = vbuf[1][cb][cj + 1];
    float g1 = vbuf[2][cb][cj + 1],  o1 = vbuf[3][cb][cj + 1];
    float i2 = vbuf[0][cb][cj + 16], f2 = vbuf[1][cb][cj + 16];
    float g2 = vbuf[2][cb][cj + 16], o2 = vbuf[3][cb][cj + 16];
    float i3 = vbuf[0][cb][cj + 17], f3 = vbuf[1][cb][cj + 17];
    float g3 = vbuf[2][cb][cj + 17], o3 = vbuf[3][cb][cj + 17];
    float c0 = sigmoidf_(f0) * creg0 + sigmoidf_(i0) * tanhf_(g0);
    float c1 = sigmoidf_(f1) * creg1 + sigmoidf_(i1) * tanhf_(g1);
    float c2 = sigmoidf_(f2) * creg2 + sigmoidf_(i2) * tanhf_(g2);
    float c3 = sigmoidf_(f3) * creg3 + sigmoidf_(i3) * tanhf_(g3);
    creg0 = c0; creg1 = c1; creg2 = c2; creg3 = c3;
    float h0 = tanhf_(c0) * sigmoidf_(o0);
    float h1 = tanhf_(c1) * sigmoidf_(o1);
    float h2 = tanhf_(c2) * sigmoidf_(o2);
    float h3 = tanhf_(c3) * sigmoidf_(o3);

    // ---- (8) tagged h stores: contiguous 128B per 8-thread group ----
    unsigned a0 = (unsigned)__builtin_bit_cast(unsigned short, (bf16)h0);
    unsigned a1 = (unsigned)__builtin_bit_cast(unsigned short, (bf16)h1);
    unsigned a2 = (unsigned)__builtin_bit_cast(unsigned short, (bf16)h2);
    unsigned a3 = (unsigned)__builtin_bit_cast(unsigned short, (bf16)h3);
    u64 tagw = (u64)(unsigned)(step + 1) << 32;
    ast64(hnext + cb * 256 + s * 16 + (tid & 7), tagw | (u64)(a0 | (a1 << 16)));
    ast64(hnext + cb * 256 + s * 16 + 8 + (tid & 7), tagw | (u64)(a2 | (a3 << 16)));

    // ---- (9) out stores (two coalesced f32 pairs) ----
    int tr = (dir == 0) ? step : ((511 - step + lenO) & 511);
    float* orow = out + (size_t)(cb * 512 + tr) * 1024 + dir * 512 + s * 32;
    *(float2*)(orow + cj) = make_float2(h0, h1);
    *(float2*)(orow + 16 + cj) = make_float2(h2, h3);
  }
}

extern "C" void kernel_launch(void* const* d_in, const int* in_sizes, int n_in,
                              void* d_out, int out_size, void* d_ws, size_t ws_size,
                              hipStream_t stream) {
  (void)in_sizes; (void)n_in; (void)out_size; (void)ws_size;
  const float* x    = (const float*)d_in[0];
  const int*   mask = (const int*)  d_in[1];
  const float* Wihf = (const float*)d_in[2];
  const float* bihf = (const float*)d_in[3];
  const float* Whhf = (const float*)d_in[4];
  const float* Wihb = (const float*)d_in[5];
  const float* bihb = (const float*)d_in[6];
  const float* Whhb = (const float*)d_in[7];
  float* out = (float*)d_out;

  char* ws = (char*)d_ws;
  u64* hbuf = (u64*)ws;                          // 2*2*32*256*8 = 262144 B
  int* lengths = (int*)(ws + 262144);            // 128 B
  const size_t head = 262144;

  hipMemsetAsync(d_ws, 0, head, stream);  // zero tags + h0 = c0 = 0 every call
  lengths_kernel<<<1, 256, 0, stream>>>(mask, lengths);
  lstm_fused<<<dim3(16, 2), 256, 0, stream>>>(
      x, Wihf, bihf, Whhf, Wihb, bihb, Whhb, lengths, hbuf, out);
}

// Round 10
// 1849.617 us; speedup vs baseline: 2.7984x; 2.7984x over previous
//
#include <hip/hip_runtime.h>
#include <hip/hip_bf16.h>

// Bidirectional LSTM, B=32 T=512 D=H=512. f32 I/O, bf16 MFMA internally.
//
// R16 = R9 protocol VERBATIM, batch dimension split into 2 independent
//       chains per direction. Grid (32 cols, 2 dir, 2 group) = 128 wgs.
//  - Batches are recurrence-independent: group g owns batches [16g,16g+16);
//    its h-exchange region in hbuf is disjoint, its chain syncs only its
//    own 32 col-wgs. 4 independent chains total (was 2).
//  - Per-wg per step: one M=16 MFMA tile (32 MFMAs, was 64), sweep = 16
//    loads/thread over 32KB (was 32/64KB), weights unchanged (128 VGPR).
//    R13/R15 lesson: cols/wg pinned at 16 by the 256-VGPR architectural
//    cap; batch split is the only participant-work reducer left.
//  - Everything else verbatim R9: step ordering, coalesced lane+64j dense
//    sweep, tagged 8B payloads, scattered-dword hA staging, 2 lgkm-only
//    barriers/step, coalesced h/out stores (threads 0-127 do the cell).

typedef __bf16 bf16;
typedef __attribute__((ext_vector_type(8))) __bf16 bf16x8;
typedef __attribute__((ext_vector_type(4))) float f32x4;
typedef unsigned long long u64;

__device__ __forceinline__ float sigmoidf_(float x) {
  return 1.f / (1.f + __expf(-x));
}
__device__ __forceinline__ float tanhf_(float x) {
  float e = __expf(-2.f * fabsf(x));
  return copysignf((1.f - e) / (1.f + e), x);
}
__device__ __forceinline__ u64 ald64(const u64* p) {
  return __hip_atomic_load(p, __ATOMIC_RELAXED, __HIP_MEMORY_SCOPE_AGENT);
}
__device__ __forceinline__ void ast64(u64* p, u64 v) {
  __hip_atomic_store(p, v, __ATOMIC_RELAXED, __HIP_MEMORY_SCOPE_AGENT);
}
__device__ __forceinline__ bf16x8 cvt8v(float4 a, float4 b) {
  bf16x8 v;
  v[0] = (bf16)a.x; v[1] = (bf16)a.y; v[2] = (bf16)a.z; v[3] = (bf16)a.w;
  v[4] = (bf16)b.x; v[5] = (bf16)b.y; v[6] = (bf16)b.z; v[7] = (bf16)b.w;
  return v;
}
// Barrier with LDS-visibility only: does NOT drain vmcnt.
__device__ __forceinline__ void bar_lgkm() {
  asm volatile("s_waitcnt lgkmcnt(0)\n\ts_barrier" ::: "memory");
}

// ---------------- lengths ----------------
__global__ void lengths_kernel(const int* __restrict__ mask, int* __restrict__ lengths) {
  __shared__ int part[32][8];
  int t = threadIdx.x;
  int b = t >> 3, sub = t & 7;
  int s = 0;
#pragma unroll 8
  for (int k = 0; k < 64; ++k) s += mask[b * 512 + sub + 8 * k];
  part[b][sub] = s;
  __syncthreads();
  if (sub == 0) {
    int tot = 0;
#pragma unroll
    for (int k = 0; k < 8; ++k) tot += part[b][k];
    lengths[b] = tot;
  }
}

// ---------------- fused persistent LSTM ----------------
__global__ __launch_bounds__(256, 1) void lstm_fused(
    const float* __restrict__ x,                                  // [32][512][512] f32
    const float* __restrict__ Wih_f, const float* __restrict__ bih_f,
    const float* __restrict__ Whh_f,
    const float* __restrict__ Wih_b, const float* __restrict__ bih_b,
    const float* __restrict__ Whh_b,
    const int* __restrict__ lengths,
    u64* __restrict__ hbuf,             // [2 dir][2 par][32 batch][256] u64 entries
    float* __restrict__ out) {          // [32][512][1024] f32
  const int s = blockIdx.x;             // h-col slice: cols [16s, 16s+16)
  const int dir = blockIdx.y;
  const int grp = blockIdx.z;           // batch group: batches [16g, 16g+16)
  const float* Wih = dir ? Wih_b : Wih_f;
  const float* Whh = dir ? Whh_b : Whh_f;
  const float* bih = dir ? bih_b : bih_f;
  const int b0 = grp * 16;              // first batch of this chain

  const int tid = threadIdx.x;
  const int lane = tid & 63, wave = tid >> 6;
  const int l15 = lane & 15, quad = lane >> 4;

  __shared__ __align__(16) bf16 xA[2][16 * 512];  // 2x16 KB x double buffer
  __shared__ __align__(16) bf16 hA[16 * 512];     // 16 KB h (single)
  __shared__ float vbuf[4][16][17];
  __shared__ int lenL[16];

  // Weight slices f32 -> bf16 registers (wave = gate; B-frag n=l15).
  bf16x8 wih[16], whh[16];
  {
    int grow = wave * 512 + s * 16 + l15;
#pragma unroll
    for (int k = 0; k < 16; ++k) {
      const float* pw = Wih + (size_t)grow * 512 + k * 32 + quad * 8;
      const float* ph = Whh + (size_t)grow * 512 + k * 32 + quad * 8;
      wih[k] = cvt8v(*(const float4*)pw, *(const float4*)(pw + 4));
      whh[k] = cvt8v(*(const float4*)ph, *(const float4*)(ph + 4));
    }
  }
  const float bv = bih[wave * 512 + s * 16 + l15];
  if (tid < 16) lenL[tid] = lengths[b0 + tid];
  __syncthreads();

  // Cell mapping (threads 0-127): cb = group-local batch, cj = col pair.
  const int cb = tid >> 3, cj = (tid & 7) * 2;
  int lenR[4];
#pragma unroll
  for (int i = 0; i < 4; ++i) lenR[i] = lenL[(i * 256 + tid) >> 6];
  const int lenO = (tid < 128) ? lenL[cb] : 0;

  float creg0 = 0.f, creg1 = 0.f;
  u64* hb = hbuf + (size_t)dir * (2 * 32 * 256);

  // Prologue: load x(0), stage xA[0], then issue prefetch of x(1).
  float4 xp[4][2];
#pragma unroll
  for (int i = 0; i < 4; ++i) {
    int c = i * 256 + tid;
    int m = c >> 6, kbp = c & 63;          // m = group-local batch [0,16)
    int kb = kbp ^ (m & 7);
    int tr = (dir == 0) ? 0 : ((511 + lenR[i]) & 511);
    const float4* p = (const float4*)(x + ((size_t)(b0 + m) * 512 + tr) * 512 + kb * 8);
    xp[i][0] = p[0]; xp[i][1] = p[1];
  }
#pragma unroll
  for (int i = 0; i < 4; ++i) {
    int c = i * 256 + tid;
    *(bf16x8*)(xA[0] + c * 8) = cvt8v(xp[i][0], xp[i][1]);
  }
#pragma unroll
  for (int i = 0; i < 4; ++i) {
    int c = i * 256 + tid;
    int m = c >> 6, kbp = c & 63;
    int kb = kbp ^ (m & 7);
    int tr = (dir == 0) ? 1 : ((510 + lenR[i]) & 511);
    const float4* p = (const float4*)(x + ((size_t)(b0 + m) * 512 + tr) * 512 + kb * 8);
    xp[i][0] = p[0]; xp[i][1] = p[1];
  }
  bar_lgkm();  // xA[0] staged

  for (int step = 0; step < 512; ++step) {
    const int par = step & 1;
    const u64* hprev = hb + (size_t)par * (32 * 256);
    u64* hnext = hb + (size_t)(par ^ 1) * (32 * 256);
    const bf16* xcur = xA[par];
    bf16* xnxt = xA[par ^ 1];

    // ---- (1) stage xA(t+1) from regs ----
    if (step < 511) {
#pragma unroll
      for (int i = 0; i < 4; ++i) {
        int c = i * 256 + tid;
        *(bf16x8*)(xnxt + c * 8) = cvt8v(xp[i][0], xp[i][1]);
      }
    }
    // ---- (2) x(t+2) prefetch issue (R9 position) ----
    if (step < 510) {
#pragma unroll
      for (int i = 0; i < 4; ++i) {
        int c = i * 256 + tid;
        int m = c >> 6, kbp = c & 63;
        int kb = kbp ^ (m & 7);
        int tr = (dir == 0) ? (step + 2) : ((509 - step + lenR[i]) & 511);
        const float4* p = (const float4*)(x + ((size_t)(b0 + m) * 512 + tr) * 512 + kb * 8);
        xp[i][0] = p[0]; xp[i][1] = p[1];
      }
    }

    // ---- (3) x-part MFMAs: v = x@Wih^T + bias (one M=16 tile) ----
    f32x4 acc0 = {bv, bv, bv, bv};
#pragma unroll
    for (int k = 0; k < 16; ++k) {
      int kb = k * 4 + quad;
      int sw = (kb ^ (l15 & 7)) * 8;
      bf16x8 ax0 = *(const bf16x8*)(xcur + l15 * 512 + sw);
      acc0 = __builtin_amdgcn_mfma_f32_16x16x32_bf16(ax0, wih[k], acc0, 0, 0, 0);
    }
    __builtin_amdgcn_sched_barrier(0);

    // ---- (4) poll (R9 verbatim): coalesced dense batched re-sweep ----
    // wave w covers group-local batches [4w,4w+4); lane reads entries
    // lane+64j (512B contiguous per load instruction).
    u64 hv[4][4];
    {
      const unsigned target = (unsigned)step;
      while (true) {
#pragma unroll
        for (int b = 0; b < 4; ++b) {
          const u64* rp = hprev + (size_t)(b0 + wave * 4 + b) * 256 + lane;
#pragma unroll
          for (int j = 0; j < 4; ++j) hv[b][j] = ald64(rp + 64 * j);
        }
        int ok = 1;
#pragma unroll
        for (int b = 0; b < 4; ++b)
#pragma unroll
          for (int j = 0; j < 4; ++j)
            ok &= (int)((unsigned)(hv[b][j] >> 32) >= target);
        if (__all(ok)) break;
        __builtin_amdgcn_s_sleep(1);
      }
    }

    // ---- (5) stage payloads -> swizzled hA (R9 verbatim layout) ----
#pragma unroll
    for (int b = 0; b < 4; ++b) {
      int m = wave * 4 + b;                     // group-local batch
#pragma unroll
      for (int j = 0; j < 4; ++j) {
        int b8 = (lane >> 2) + 16 * j;          // 8-col block of col 2*(lane+64j)
        int b8s = b8 ^ (m & 7);                 // same XOR swizzle as MFMA reads
        *(unsigned*)(hA + m * 512 + b8s * 8 + 2 * (lane & 3)) = (unsigned)hv[b][j];
      }
    }
    bar_lgkm();  // C: hA + xnxt visible (x prefetch rides through)

    // ---- (6) h-part MFMAs: v += h@Whh^T ----
#pragma unroll
    for (int k = 0; k < 16; ++k) {
      int kb = k * 4 + quad;
      int sw = (kb ^ (l15 & 7)) * 8;
      bf16x8 ah0 = *(const bf16x8*)(hA + l15 * 512 + sw);
      acc0 = __builtin_amdgcn_mfma_f32_16x16x32_bf16(ah0, whh[k], acc0, 0, 0, 0);
    }
#pragma unroll
    for (int r = 0; r < 4; ++r)
      vbuf[wave][quad * 4 + r][l15] = acc0[r];
    bar_lgkm();  // D: vbuf ready

    // ---- (7) cell + stores: threads 0-127 (16 batches x 8 col-pairs) ----
    if (tid < 128) {
      float i0 = vbuf[0][cb][cj],     f0 = vbuf[1][cb][cj];
      float g0 = vbuf[2][cb][cj],     o0 = vbuf[3][cb][cj];
      float i1 = vbuf[0][cb][cj + 1], f1 = vbuf[1][cb][cj + 1];
      float g1 = vbuf[2][cb][cj + 1], o1 = vbuf[3][cb][cj + 1];
      float c0 = sigmoidf_(f0) * creg0 + sigmoidf_(i0) * tanhf_(g0);
      float c1 = sigmoidf_(f1) * creg1 + sigmoidf_(i1) * tanhf_(g1);
      creg0 = c0; creg1 = c1;
      float h0 = tanhf_(c0) * sigmoidf_(o0);
      float h1 = tanhf_(c1) * sigmoidf_(o1);

      // tagged h store: coalesced 64B line per 8 lanes
      unsigned ulo = (unsigned)__builtin_bit_cast(unsigned short, (bf16)h0);
      unsigned uhi = (unsigned)__builtin_bit_cast(unsigned short, (bf16)h1);
      u64 pk = ((u64)(unsigned)(step + 1) << 32) | (u64)(ulo | (uhi << 16));
      ast64(hnext + (size_t)(b0 + cb) * 256 + s * 8 + (tid & 7), pk);

      // out store (coalesced 64B per 8-thread group)
      int tr = (dir == 0) ? step : ((511 - step + lenO) & 511);
      *(float2*)(out + (size_t)((b0 + cb) * 512 + tr) * 1024 + dir * 512 + s * 16 + cj) =
          make_float2(h0, h1);
    }
  }
}

extern "C" void kernel_launch(void* const* d_in, const int* in_sizes, int n_in,
                              void* d_out, int out_size, void* d_ws, size_t ws_size,
                              hipStream_t stream) {
  (void)in_sizes; (void)n_in; (void)out_size; (void)ws_size;
  const float* x    = (const float*)d_in[0];
  const int*   mask = (const int*)  d_in[1];
  const float* Wihf = (const float*)d_in[2];
  const float* bihf = (const float*)d_in[3];
  const float* Whhf = (const float*)d_in[4];
  const float* Wihb = (const float*)d_in[5];
  const float* bihb = (const float*)d_in[6];
  const float* Whhb = (const float*)d_in[7];
  float* out = (float*)d_out;

  char* ws = (char*)d_ws;
  u64* hbuf = (u64*)ws;                          // 2*2*32*256*8 = 262144 B
  int* lengths = (int*)(ws + 262144);            // 128 B
  const size_t head = 262144;

  hipMemsetAsync(d_ws, 0, head, stream);  // zero tags + h0 = c0 = 0 every call
  lengths_kernel<<<1, 256, 0, stream>>>(mask, lengths);
  lstm_fused<<<dim3(32, 2, 2), 256, 0, stream>>>(
      x, Wihf, bihf, Whhf, Wihb, bihb, Whhb, lengths, hbuf, out);
}

// Round 11
// 1505.860 us; speedup vs baseline: 3.4372x; 1.2283x over previous
//
#include <hip/hip_runtime.h>
#include <hip/hip_bf16.h>

// Bidirectional LSTM, B=32 T=512 D=H=512. f32 I/O, bf16 MFMA internally.
//
// R17 = R16 protocol VERBATIM, batch split deepened: 4 independent chains
//       per direction (8 batches each). Grid (32 cols, 2 dir, 4 grp) =
//       256 wgs = all 256 CUs (R16 left half the GPU idle).
//  - Mechanism (validated by R16's 2110->1786): smaller per-step sweep per
//    consumer (now 8 loads/thread over 16KB, was 16/32KB) + more chains
//    staggering their LLC bursts (8 chains, was 4).
//  - M=16 MFMA tile now has 8 valid batch rows; rows 8-15 of xA/hA zeroed
//    once at init -> dead half computes zeros, discarded (cell reads rows
//    0-7 only). MFMA issue is <10% of step time; waste is irrelevant.
//  - Everything else verbatim R9/R16: step ordering, coalesced lane+64j
//    dense sweep, tagged 8B payloads, scattered-dword hA staging, 2
//    lgkm-only barriers/step, coalesced h/out stores.

typedef __bf16 bf16;
typedef __attribute__((ext_vector_type(8))) __bf16 bf16x8;
typedef __attribute__((ext_vector_type(4))) float f32x4;
typedef unsigned long long u64;

__device__ __forceinline__ float sigmoidf_(float x) {
  return 1.f / (1.f + __expf(-x));
}
__device__ __forceinline__ float tanhf_(float x) {
  float e = __expf(-2.f * fabsf(x));
  return copysignf((1.f - e) / (1.f + e), x);
}
__device__ __forceinline__ u64 ald64(const u64* p) {
  return __hip_atomic_load(p, __ATOMIC_RELAXED, __HIP_MEMORY_SCOPE_AGENT);
}
__device__ __forceinline__ void ast64(u64* p, u64 v) {
  __hip_atomic_store(p, v, __ATOMIC_RELAXED, __HIP_MEMORY_SCOPE_AGENT);
}
__device__ __forceinline__ bf16x8 cvt8v(float4 a, float4 b) {
  bf16x8 v;
  v[0] = (bf16)a.x; v[1] = (bf16)a.y; v[2] = (bf16)a.z; v[3] = (bf16)a.w;
  v[4] = (bf16)b.x; v[5] = (bf16)b.y; v[6] = (bf16)b.z; v[7] = (bf16)b.w;
  return v;
}
// Barrier with LDS-visibility only: does NOT drain vmcnt.
__device__ __forceinline__ void bar_lgkm() {
  asm volatile("s_waitcnt lgkmcnt(0)\n\ts_barrier" ::: "memory");
}

// ---------------- lengths ----------------
__global__ void lengths_kernel(const int* __restrict__ mask, int* __restrict__ lengths) {
  __shared__ int part[32][8];
  int t = threadIdx.x;
  int b = t >> 3, sub = t & 7;
  int s = 0;
#pragma unroll 8
  for (int k = 0; k < 64; ++k) s += mask[b * 512 + sub + 8 * k];
  part[b][sub] = s;
  __syncthreads();
  if (sub == 0) {
    int tot = 0;
#pragma unroll
    for (int k = 0; k < 8; ++k) tot += part[b][k];
    lengths[b] = tot;
  }
}

// ---------------- fused persistent LSTM ----------------
__global__ __launch_bounds__(256, 1) void lstm_fused(
    const float* __restrict__ x,                                  // [32][512][512] f32
    const float* __restrict__ Wih_f, const float* __restrict__ bih_f,
    const float* __restrict__ Whh_f,
    const float* __restrict__ Wih_b, const float* __restrict__ bih_b,
    const float* __restrict__ Whh_b,
    const int* __restrict__ lengths,
    u64* __restrict__ hbuf,             // [2 dir][2 par][32 batch][256] u64 entries
    float* __restrict__ out) {          // [32][512][1024] f32
  const int s = blockIdx.x;             // h-col slice: cols [16s, 16s+16)
  const int dir = blockIdx.y;
  const int grp = blockIdx.z;           // batch group: batches [8g, 8g+8)
  const float* Wih = dir ? Wih_b : Wih_f;
  const float* Whh = dir ? Whh_b : Whh_f;
  const float* bih = dir ? bih_b : bih_f;
  const int b0 = grp * 8;               // first batch of this chain

  const int tid = threadIdx.x;
  const int lane = tid & 63, wave = tid >> 6;
  const int l15 = lane & 15, quad = lane >> 4;

  // 16 rows allocated (MFMA A-tile is M=16); rows 8-15 zeroed once.
  __shared__ __align__(16) bf16 xA[2][16 * 512];  // 2x16 KB
  __shared__ __align__(16) bf16 hA[16 * 512];     // 16 KB
  __shared__ float vbuf[4][16][17];
  __shared__ int lenL[8];

  // Weight slices f32 -> bf16 registers (wave = gate; B-frag n=l15).
  bf16x8 wih[16], whh[16];
  {
    int grow = wave * 512 + s * 16 + l15;
#pragma unroll
    for (int k = 0; k < 16; ++k) {
      const float* pw = Wih + (size_t)grow * 512 + k * 32 + quad * 8;
      const float* ph = Whh + (size_t)grow * 512 + k * 32 + quad * 8;
      wih[k] = cvt8v(*(const float4*)pw, *(const float4*)(pw + 4));
      whh[k] = cvt8v(*(const float4*)ph, *(const float4*)(ph + 4));
    }
  }
  const float bv = bih[wave * 512 + s * 16 + l15];
  if (tid < 8) lenL[tid] = lengths[b0 + tid];

  // Zero dead rows 8-15 of xA[0], xA[1], hA (one-time; 24KB total).
  {
    // 3 buffers x 8 rows x 512 bf16 = 12288 bf16 = 1536 x 16B chunks.
    for (int c = tid; c < 1536; c += 256) {
      int buf = c >> 9, r = (c >> 6) & 7, off = (c & 63) * 8;
      bf16* dst = (buf == 0) ? (xA[0] + (8 + r) * 512 + off)
                : (buf == 1) ? (xA[1] + (8 + r) * 512 + off)
                             : (hA + (8 + r) * 512 + off);
      *(ulonglong2*)dst = make_ulonglong2(0ull, 0ull);
    }
  }
  __syncthreads();

  // Cell mapping (threads 0-63): cb = group-local batch, cj = col pair.
  const int cb = tid >> 3, cj = (tid & 7) * 2;
  int lenR[2];
#pragma unroll
  for (int i = 0; i < 2; ++i) lenR[i] = lenL[(i * 256 + tid) >> 6];
  const int lenO = (tid < 64) ? lenL[cb] : 0;

  float creg0 = 0.f, creg1 = 0.f;
  u64* hb = hbuf + (size_t)dir * (2 * 32 * 256);

  // Prologue: load x(0), stage xA[0], then issue prefetch of x(1).
  float4 xp[2][2];
#pragma unroll
  for (int i = 0; i < 2; ++i) {
    int c = i * 256 + tid;
    int m = c >> 6, kbp = c & 63;          // m = group-local batch [0,8)
    int kb = kbp ^ (m & 7);
    int tr = (dir == 0) ? 0 : ((511 + lenR[i]) & 511);
    const float4* p = (const float4*)(x + ((size_t)(b0 + m) * 512 + tr) * 512 + kb * 8);
    xp[i][0] = p[0]; xp[i][1] = p[1];
  }
#pragma unroll
  for (int i = 0; i < 2; ++i) {
    int c = i * 256 + tid;
    *(bf16x8*)(xA[0] + c * 8) = cvt8v(xp[i][0], xp[i][1]);
  }
#pragma unroll
  for (int i = 0; i < 2; ++i) {
    int c = i * 256 + tid;
    int m = c >> 6, kbp = c & 63;
    int kb = kbp ^ (m & 7);
    int tr = (dir == 0) ? 1 : ((510 + lenR[i]) & 511);
    const float4* p = (const float4*)(x + ((size_t)(b0 + m) * 512 + tr) * 512 + kb * 8);
    xp[i][0] = p[0]; xp[i][1] = p[1];
  }
  bar_lgkm();  // xA[0] staged

  for (int step = 0; step < 512; ++step) {
    const int par = step & 1;
    const u64* hprev = hb + (size_t)par * (32 * 256);
    u64* hnext = hb + (size_t)(par ^ 1) * (32 * 256);
    const bf16* xcur = xA[par];
    bf16* xnxt = xA[par ^ 1];

    // ---- (1) stage xA(t+1) from regs ----
    if (step < 511) {
#pragma unroll
      for (int i = 0; i < 2; ++i) {
        int c = i * 256 + tid;
        *(bf16x8*)(xnxt + c * 8) = cvt8v(xp[i][0], xp[i][1]);
      }
    }
    // ---- (2) x(t+2) prefetch issue (R9 position) ----
    if (step < 510) {
#pragma unroll
      for (int i = 0; i < 2; ++i) {
        int c = i * 256 + tid;
        int m = c >> 6, kbp = c & 63;
        int kb = kbp ^ (m & 7);
        int tr = (dir == 0) ? (step + 2) : ((509 - step + lenR[i]) & 511);
        const float4* p = (const float4*)(x + ((size_t)(b0 + m) * 512 + tr) * 512 + kb * 8);
        xp[i][0] = p[0]; xp[i][1] = p[1];
      }
    }

    // ---- (3) x-part MFMAs: v = x@Wih^T + bias (one M=16 tile) ----
    f32x4 acc0 = {bv, bv, bv, bv};
#pragma unroll
    for (int k = 0; k < 16; ++k) {
      int kb = k * 4 + quad;
      int sw = (kb ^ (l15 & 7)) * 8;
      bf16x8 ax0 = *(const bf16x8*)(xcur + l15 * 512 + sw);
      acc0 = __builtin_amdgcn_mfma_f32_16x16x32_bf16(ax0, wih[k], acc0, 0, 0, 0);
    }
    __builtin_amdgcn_sched_barrier(0);

    // ---- (4) poll (R9 verbatim): coalesced dense batched re-sweep ----
    // wave w covers group-local batches [2w,2w+2); lane reads entries
    // lane+64j (512B contiguous per load instruction).
    u64 hv[2][4];
    {
      const unsigned target = (unsigned)step;
      while (true) {
#pragma unroll
        for (int b = 0; b < 2; ++b) {
          const u64* rp = hprev + (size_t)(b0 + wave * 2 + b) * 256 + lane;
#pragma unroll
          for (int j = 0; j < 4; ++j) hv[b][j] = ald64(rp + 64 * j);
        }
        int ok = 1;
#pragma unroll
        for (int b = 0; b < 2; ++b)
#pragma unroll
          for (int j = 0; j < 4; ++j)
            ok &= (int)((unsigned)(hv[b][j] >> 32) >= target);
        if (__all(ok)) break;
        __builtin_amdgcn_s_sleep(1);
      }
    }

    // ---- (5) stage payloads -> swizzled hA (R9 verbatim layout) ----
#pragma unroll
    for (int b = 0; b < 2; ++b) {
      int m = wave * 2 + b;                     // group-local batch [0,8)
#pragma unroll
      for (int j = 0; j < 4; ++j) {
        int b8 = (lane >> 2) + 16 * j;          // 8-col block of col 2*(lane+64j)
        int b8s = b8 ^ (m & 7);                 // same XOR swizzle as MFMA reads
        *(unsigned*)(hA + m * 512 + b8s * 8 + 2 * (lane & 3)) = (unsigned)hv[b][j];
      }
    }
    bar_lgkm();  // C: hA + xnxt visible (x prefetch rides through)

    // ---- (6) h-part MFMAs: v += h@Whh^T ----
#pragma unroll
    for (int k = 0; k < 16; ++k) {
      int kb = k * 4 + quad;
      int sw = (kb ^ (l15 & 7)) * 8;
      bf16x8 ah0 = *(const bf16x8*)(hA + l15 * 512 + sw);
      acc0 = __builtin_amdgcn_mfma_f32_16x16x32_bf16(ah0, whh[k], acc0, 0, 0, 0);
    }
#pragma unroll
    for (int r = 0; r < 4; ++r)
      vbuf[wave][quad * 4 + r][l15] = acc0[r];
    bar_lgkm();  // D: vbuf ready

    // ---- (7) cell + stores: threads 0-63 (8 batches x 8 col-pairs) ----
    if (tid < 64) {
      float i0 = vbuf[0][cb][cj],     f0 = vbuf[1][cb][cj];
      float g0 = vbuf[2][cb][cj],     o0 = vbuf[3][cb][cj];
      float i1 = vbuf[0][cb][cj + 1], f1 = vbuf[1][cb][cj + 1];
      float g1 = vbuf[2][cb][cj + 1], o1 = vbuf[3][cb][cj + 1];
      float c0 = sigmoidf_(f0) * creg0 + sigmoidf_(i0) * tanhf_(g0);
      float c1 = sigmoidf_(f1) * creg1 + sigmoidf_(i1) * tanhf_(g1);
      creg0 = c0; creg1 = c1;
      float h0 = tanhf_(c0) * sigmoidf_(o0);
      float h1 = tanhf_(c1) * sigmoidf_(o1);

      // tagged h store: coalesced 64B line per 8 lanes
      unsigned ulo = (unsigned)__builtin_bit_cast(unsigned short, (bf16)h0);
      unsigned uhi = (unsigned)__builtin_bit_cast(unsigned short, (bf16)h1);
      u64 pk = ((u64)(unsigned)(step + 1) << 32) | (u64)(ulo | (uhi << 16));
      ast64(hnext + (size_t)(b0 + cb) * 256 + s * 8 + (tid & 7), pk);

      // out store (coalesced 64B per 8-thread group)
      int tr = (dir == 0) ? step : ((511 - step + lenO) & 511);
      *(float2*)(out + (size_t)((b0 + cb) * 512 + tr) * 1024 + dir * 512 + s * 16 + cj) =
          make_float2(h0, h1);
    }
  }
}

extern "C" void kernel_launch(void* const* d_in, const int* in_sizes, int n_in,
                              void* d_out, int out_size, void* d_ws, size_t ws_size,
                              hipStream_t stream) {
  (void)in_sizes; (void)n_in; (void)out_size; (void)ws_size;
  const float* x    = (const float*)d_in[0];
  const int*   mask = (const int*)  d_in[1];
  const float* Wihf = (const float*)d_in[2];
  const float* bihf = (const float*)d_in[3];
  const float* Whhf = (const float*)d_in[4];
  const float* Wihb = (const float*)d_in[5];
  const float* bihb = (const float*)d_in[6];
  const float* Whhb = (const float*)d_in[7];
  float* out = (float*)d_out;

  char* ws = (char*)d_ws;
  u64* hbuf = (u64*)ws;                          // 2*2*32*256*8 = 262144 B
  int* lengths = (int*)(ws + 262144);            // 128 B
  const size_t head = 262144;

  hipMemsetAsync(d_ws, 0, head, stream);  // zero tags + h0 = c0 = 0 every call
  lengths_kernel<<<1, 256, 0, stream>>>(mask, lengths);
  lstm_fused<<<dim3(32, 2, 4), 256, 0, stream>>>(
      x, Wihf, bihf, Whhf, Wihb, bihb, Whhb, lengths, hbuf, out);
}